// Round 4
// baseline (3550.287 us; speedup 1.0000x reference)
//
#include <hip/hip_runtime.h>

#define T_STEPS 128
#define BATCH   128
#define DX      1024
#define DH      1024
#define BDH     (BATCH * DH)   // 131072
#define BDX     (BATCH * DX)

typedef __attribute__((ext_vector_type(8)))  short short8;
typedef __attribute__((ext_vector_type(16))) float f32x16;

static __device__ __forceinline__ unsigned short f2bf(float f) {
    union { float f; unsigned u; } v; v.f = f;
    unsigned r = v.u + 0x7fffu + ((v.u >> 16) & 1u);   // RNE
    return (unsigned short)(r >> 16);
}

static __device__ __forceinline__ float sigf(float x) {
    float u = __expf(-fabsf(x));
    float b = 1.0f / (1.0f + u);
    return x >= 0.0f ? b : 1.0f - b;
}
static __device__ __forceinline__ float tanhfast(float x) {
    float u = __expf(-2.0f * fabsf(x));
    float r = (1.0f - u) / (1.0f + u);
    return x >= 0.0f ? r : -r;
}

__global__ __launch_bounds__(256) void init_seed(const float* __restrict__ h0,
                                                 unsigned short* __restrict__ hseq,
                                                 unsigned* __restrict__ gflag) {
    const int i = blockIdx.x * 256 + threadIdx.x;
    if (i < BDH) hseq[i] = f2bf(h0[i]);
    if (blockIdx.x == 0) gflag[threadIdx.x] = 0;     // 256 flag words
}

// Persistent, wave-specialized. 256 WGs (1/CU): bid = js*2 + bhh.
// WG owns j-cols [js*8,+8) (perm rows p = g*8+jj, gates F,G,O,R; I elided)
// and batch rows [bhh*64,+64). LDS: Wx slab 64K + Wh slab 64K (XOR-swizzled),
// plx/plh [2 tiles][32][36] f32, flags.
// Waves 0,1: x-GEMM (M-tile=wave, full Kx=1024) -> plx, flag handshake.
// Waves 2,3: h-GEMM (M-tile=wave-2, full Kh=1024) + fused epilogue; c in regs;
// h passes steps via hseq ring (agent-scope stores); inter-WG sync via 128
// per-WG flags per batch-half (release store, relaxed polling).
__global__ __launch_bounds__(256, 1) void eplstm(
    const float* __restrict__ xg,   const float* __restrict__ mem,
    const float* __restrict__ Wx,   const float* __restrict__ Wh,
    const float* __restrict__ bx,   const float* __restrict__ bhp,
    const float* __restrict__ c0,
    unsigned short* __restrict__ hseq, float* __restrict__ out,
    unsigned* __restrict__ gflag)
{
    extern __shared__ char smem[];
    float* plx = (float*)(smem + 131072);              // [2][32][36] f32
    float* plh = (float*)(smem + 131072 + 9216);       // [2][32][36] f32
    unsigned* lflag = (unsigned*)(smem + 131072 + 18432); // xready[2], xfree[2], hdone

    const int bid = blockIdx.x;
    const int js = bid >> 1, bhh = bid & 1;
    const int tid = threadIdx.x;
    const int wave = tid >> 6, lane = tid & 63;

    // ---- one-time: stage both weight slabs into LDS (bf16, XOR-swizzled) ----
    {
        const int row = tid >> 3;                       // perm row 0..31
        const int g = row >> 3, jj = row & 7;
        const int srow = (g + 1) * 1024 + js * 8 + jj;  // skip I-gate chunk
        const int sw = (row & 7) << 4;
        for (int c = 0; c < 2; ++c) {
            const float* W = (c ? Wh : Wx) + (size_t)srow * 1024;
            char* dst = smem + c * 65536 + row * 2048;
            for (int it = 0; it < 16; ++it) {
                const int k = (tid & 7) * 128 + it * 8;
                float4 lo = *(const float4*)(W + k);
                float4 hi = *(const float4*)(W + k + 4);
                union { unsigned short u[8]; short8 v; } pk;
                pk.u[0]=f2bf(lo.x); pk.u[1]=f2bf(lo.y); pk.u[2]=f2bf(lo.z); pk.u[3]=f2bf(lo.w);
                pk.u[4]=f2bf(hi.x); pk.u[5]=f2bf(hi.y); pk.u[6]=f2bf(hi.z); pk.u[7]=f2bf(hi.w);
                *(short8*)(dst + ((k * 2) ^ sw)) = pk.v;
            }
        }
    }
    if (tid < 8) lflag[tid] = 0;
    __syncthreads();                                    // only WG-wide sync

    const int mt   = wave & 1;
    const bool ish = wave >= 2;
    const int arow = bhh * 64 + mt * 32 + (lane & 31);
    const int k8   = (lane >> 5) * 8;
    const char* wrow = smem + (ish ? 65536 : 0) + (lane & 31) * 2048;
    const int sw2  = ((lane & 31) & 7) << 4;
    const int koff = k8 * 2;
    const int p    = lane & 31;
    const int word = (p & 7) * 4 + (p >> 3);            // pl col: jj*4 + gate

    if (!ish) {
        // ---------------- X waves: no sequential dependency ----------------
        unsigned* xready = &lflag[mt];
        unsigned* xfree  = &lflag[2 + mt];
        float* pb = plx + mt * 1152;
        for (int t = 0; t < T_STEPS; ++t) {
            while (__hip_atomic_load(xfree, __ATOMIC_ACQUIRE,
                                     __HIP_MEMORY_SCOPE_WORKGROUP) < (unsigned)t) {}
            const float* xp = xg + (size_t)t * BDX + (size_t)arow * DX + k8;
            f32x16 a0 = {}, a1 = {};
            #pragma unroll 8
            for (int ks = 0; ks < 64; ++ks) {
                float4 lo = *(const float4*)(xp + ks * 16);
                float4 hi = *(const float4*)(xp + ks * 16 + 4);
                union { unsigned u32[4]; short8 v; } pk;   // bf16 truncation packs
                pk.u32[0] = __builtin_amdgcn_perm(__float_as_uint(lo.y), __float_as_uint(lo.x), 0x07060302u);
                pk.u32[1] = __builtin_amdgcn_perm(__float_as_uint(lo.w), __float_as_uint(lo.z), 0x07060302u);
                pk.u32[2] = __builtin_amdgcn_perm(__float_as_uint(hi.y), __float_as_uint(hi.x), 0x07060302u);
                pk.u32[3] = __builtin_amdgcn_perm(__float_as_uint(hi.w), __float_as_uint(hi.z), 0x07060302u);
                short8 b = *(const short8*)(wrow + ((ks * 32 + koff) ^ sw2));
                if (ks & 1) a1 = __builtin_amdgcn_mfma_f32_32x32x16_bf16(pk.v, b, a1, 0, 0, 0);
                else        a0 = __builtin_amdgcn_mfma_f32_32x32x16_bf16(pk.v, b, a0, 0, 0, 0);
            }
            f32x16 r = a0 + a1;
            #pragma unroll
            for (int i = 0; i < 16; ++i) {
                const int rowc = (i & 3) + 8 * (i >> 2) + 4 * (lane >> 5);
                pb[rowc * 36 + word] = r[i];
            }
            __hip_atomic_store(xready, (unsigned)(t + 1), __ATOMIC_RELEASE,
                               __HIP_MEMORY_SCOPE_WORKGROUP);
        }
    } else {
        // ---------------- H waves: the sequential critical path ----------------
        unsigned* xready = &lflag[mt];
        unsigned* xfree  = &lflag[2 + mt];
        unsigned* hdone  = &lflag[4];
        const float* pbx = plx + mt * 1152;
        float* pbh = plh + mt * 1152;
        const int rl  = lane >> 1;
        const int jj0 = (lane & 1) * 4;
        const int orow = bhh * 64 + mt * 32 + rl;
        const size_t obase = (size_t)orow * DH + js * 8 + jj0;
        float4 bias[4];
        #pragma unroll
        for (int g = 0; g < 4; ++g) {
            float4 vx = *(const float4*)(bx  + (g + 1) * 1024 + js * 8 + jj0);
            float4 vh = *(const float4*)(bhp + (g + 1) * 1024 + js * 8 + jj0);
            bias[g] = make_float4(vx.x+vh.x, vx.y+vh.y, vx.z+vh.z, vx.w+vh.w);
        }
        float4 c = *(const float4*)(c0 + obase);
        unsigned long long* fb = (unsigned long long*)(gflag + bhh * 128);

        for (int t = 0; t < T_STEPS; ++t) {
            float4 mv = *(const float4*)(mem + (size_t)t * BDH + obase);
            // wait: all 128 js-producers of this batch-half finished step t-1
            for (;;) {
                unsigned long long fv = __hip_atomic_load(&fb[lane], __ATOMIC_RELAXED,
                                                          __HIP_MEMORY_SCOPE_AGENT);
                unsigned f0 = (unsigned)fv, f1 = (unsigned)(fv >> 32);
                if (__all(f0 >= (unsigned)t && f1 >= (unsigned)t)) break;
                __builtin_amdgcn_s_sleep(2);
            }
            const unsigned short* hp = hseq + (size_t)t * BDH + (size_t)arow * DH + k8;
            f32x16 a0 = {}, a1 = {};
            #pragma unroll 8
            for (int ks = 0; ks < 64; ++ks) {
                short8 a = *(const short8*)(hp + ks * 16);
                short8 b = *(const short8*)(wrow + ((ks * 32 + koff) ^ sw2));
                if (ks & 1) a1 = __builtin_amdgcn_mfma_f32_32x32x16_bf16(a, b, a1, 0, 0, 0);
                else        a0 = __builtin_amdgcn_mfma_f32_32x32x16_bf16(a, b, a0, 0, 0, 0);
            }
            f32x16 r = a0 + a1;
            #pragma unroll
            for (int i = 0; i < 16; ++i) {
                const int rowc = (i & 3) + 8 * (i >> 2) + 4 * (lane >> 5);
                pbh[rowc * 36 + word] = r[i];
            }
            while (__hip_atomic_load(xready, __ATOMIC_ACQUIRE,
                                     __HIP_MEMORY_SCOPE_WORKGROUP) < (unsigned)(t + 1)) {}
            float hv[4];
            float cc[4] = {c.x, c.y, c.z, c.w};
            float mm[4] = {mv.x, mv.y, mv.z, mv.w};
            #pragma unroll
            for (int e = 0; e < 4; ++e) {
                float4 px = *(const float4*)(pbx + rl * 36 + (jj0 + e) * 4);
                float4 ph = *(const float4*)(pbh + rl * 36 + (jj0 + e) * 4);
                float gF = px.x + ph.x + ((const float*)&bias[0])[e];
                float gG = px.y + ph.y + ((const float*)&bias[1])[e];
                float gO = px.z + ph.z + ((const float*)&bias[2])[e];
                float gR = px.w + ph.w + ((const float*)&bias[3])[e];
                float ft = sigf(gF);
                float gt = tanhfast(gG);
                float ot = sigf(gO);
                float rt = sigf(gR);
                float cv = ft * cc[e] + (1.f - ft) * gt + rt * tanhfast(mm[e]);
                cc[e] = cv;
                hv[e] = ot * tanhfast(cv);
            }
            c = make_float4(cc[0], cc[1], cc[2], cc[3]);
            __hip_atomic_store(xfree, (unsigned)(t + 1), __ATOMIC_RELEASE,
                               __HIP_MEMORY_SCOPE_WORKGROUP);
            *(float4*)(out + (size_t)t * BDH + obase) = make_float4(hv[0], hv[1], hv[2], hv[3]);
            unsigned long long hpack =
                  (unsigned long long)f2bf(hv[0])
                | ((unsigned long long)f2bf(hv[1]) << 16)
                | ((unsigned long long)f2bf(hv[2]) << 32)
                | ((unsigned long long)f2bf(hv[3]) << 48);
            __hip_atomic_store((unsigned long long*)(hseq + (size_t)(t + 1) * BDH + obase),
                               hpack, __ATOMIC_RELAXED, __HIP_MEMORY_SCOPE_AGENT);
            asm volatile("s_waitcnt vmcnt(0)" ::: "memory");
            if (lane == 0) {
                unsigned old = __hip_atomic_fetch_add(hdone, 1u, __ATOMIC_ACQ_REL,
                                                      __HIP_MEMORY_SCOPE_WORKGROUP);
                if (old & 1u) {   // second h-wave of this WG for step t
                    __hip_atomic_store(&gflag[bhh * 128 + js], (unsigned)(t + 1),
                                       __ATOMIC_RELEASE, __HIP_MEMORY_SCOPE_AGENT);
                }
            }
        }
    }
}

extern "C" void kernel_launch(void* const* d_in, const int* in_sizes, int n_in,
                              void* d_out, int out_size, void* d_ws, size_t ws_size,
                              hipStream_t stream) {
    const float* inputs   = (const float*)d_in[0];
    const float* memories = (const float*)d_in[1];
    const float* h0       = (const float*)d_in[2];
    const float* c0       = (const float*)d_in[3];
    const float* Wx       = (const float*)d_in[4];
    const float* bx       = (const float*)d_in[5];
    const float* Wh       = (const float*)d_in[6];
    const float* bh_      = (const float*)d_in[7];
    float* outp = (float*)d_out;

    char* ws = (char*)d_ws;
    unsigned*       gflag = (unsigned*)ws;                       // 1 KiB
    unsigned short* hseq  = (unsigned short*)(ws + 1024);        // (T+1)*BDH bf16

    init_seed<<<512, 256, 0, stream>>>(h0, hseq, gflag);

    const unsigned smem_bytes = 131072 + 9216 + 9216 + 64;       // 149568
    (void)hipFuncSetAttribute((const void*)eplstm,
                              hipFuncAttributeMaxDynamicSharedMemorySize, smem_bytes);
    void* kargs[] = { (void*)&inputs, (void*)&memories, (void*)&Wx, (void*)&Wh,
                      (void*)&bx, (void*)&bh_, (void*)&c0, (void*)&hseq,
                      (void*)&outp, (void*)&gflag };
    hipError_t err = hipLaunchCooperativeKernel((const void*)eplstm, dim3(256),
                                                dim3(256), kargs, smem_bytes, stream);
    if (err != hipSuccess) {
        eplstm<<<256, 256, smem_bytes, stream>>>(inputs, memories, Wx, Wh, bx, bh_,
                                                 c0, hseq, outp, gflag);
    }
}

// Round 5
// 3139.547 us; speedup vs baseline: 1.1308x; 1.1308x over previous
//
#include <hip/hip_runtime.h>

#define T_STEPS 128
#define BATCH   128
#define DX      1024
#define DH      1024
#define BDH     (BATCH * DH)   // 131072
#define BDX     (BATCH * DX)
#define PLW     40             // pl row stride (words), 160B => 16B-aligned rows

typedef __attribute__((ext_vector_type(8)))  short short8;
typedef __attribute__((ext_vector_type(16))) float f32x16;

static __device__ __forceinline__ unsigned short f2bf(float f) {
    union { float f; unsigned u; } v; v.f = f;
    unsigned r = v.u + 0x7fffu + ((v.u >> 16) & 1u);   // RNE
    return (unsigned short)(r >> 16);
}
static __device__ __forceinline__ float sigf(float x) {
    float u = __expf(-fabsf(x));
    float b = 1.0f / (1.0f + u);
    return x >= 0.0f ? b : 1.0f - b;
}
static __device__ __forceinline__ float tanhfast(float x) {
    float u = __expf(-2.0f * fabsf(x));
    float r = (1.0f - u) / (1.0f + u);
    return x >= 0.0f ? r : -r;
}

// ---------------- shared prep kernels ----------------

__global__ __launch_bounds__(256) void prep_x(const float* __restrict__ x,
                                              unsigned short* __restrict__ Xb) {
    const size_t i8 = ((size_t)blockIdx.x * 256 + threadIdx.x) * 8;
    float4 lo = reinterpret_cast<const float4*>(x + i8)[0];
    float4 hi = reinterpret_cast<const float4*>(x + i8)[1];
    union { unsigned short u[8]; short8 v; } pk;
    pk.u[0]=f2bf(lo.x); pk.u[1]=f2bf(lo.y); pk.u[2]=f2bf(lo.z); pk.u[3]=f2bf(lo.w);
    pk.u[4]=f2bf(hi.x); pk.u[5]=f2bf(hi.y); pk.u[6]=f2bf(hi.z); pk.u[7]=f2bf(hi.w);
    *reinterpret_cast<short8*>(Xb + i8) = pk.v;
}

__global__ __launch_bounds__(256) void init_seed(const float* __restrict__ h0,
                                                 unsigned short* __restrict__ hseq,
                                                 unsigned* __restrict__ gflag) {
    const int i = blockIdx.x * 256 + threadIdx.x;
    if (i < BDH) hseq[i] = f2bf(h0[i]);
    if (blockIdx.x == 0) gflag[threadIdx.x] = 0;     // 256 flag words
}

// Wxp[p][k] bf16 (perm row p = js*32 + g*8 + jj, gates F,G,O,R; I elided),
// bp[p] = bx+bh folded bias.
__global__ __launch_bounds__(128) void prep_wxp(const float* __restrict__ Wx,
                                                const float* __restrict__ bx,
                                                const float* __restrict__ bh,
                                                unsigned short* __restrict__ Wxp,
                                                float* __restrict__ bp) {
    const int p = blockIdx.x;                        // 0..4095
    const int js = p >> 5, g = (p >> 3) & 3, jj = p & 7;
    const int srow = (g + 1) * 1024 + js * 8 + jj;
    const int k = threadIdx.x * 8;                   // 0..1016
    float4 lo = *(const float4*)(Wx + (size_t)srow * DX + k);
    float4 hi = *(const float4*)(Wx + (size_t)srow * DX + k + 4);
    union { unsigned short u[8]; short8 v; } pk;
    pk.u[0]=f2bf(lo.x); pk.u[1]=f2bf(lo.y); pk.u[2]=f2bf(lo.z); pk.u[3]=f2bf(lo.w);
    pk.u[4]=f2bf(hi.x); pk.u[5]=f2bf(hi.y); pk.u[6]=f2bf(hi.z); pk.u[7]=f2bf(hi.w);
    *reinterpret_cast<short8*>(Wxp + (size_t)p * 1024 + k) = pk.v;
    if (threadIdx.x == 0) bp[p] = bx[srow] + bh[srow];
}

// ---------------- Tier A: Gx prepass (parallel over all timesteps) ----------------
// Grid 16384: c=bid&7 (XCD chunk), i=bid>>3: mt = c*16 + (i>>7) == timestep t,
// js = i&127. WG: M-tile = 128 rows (all of batch at step t), N = 32 perm rows.
// Gx[m][jcol][g] f16, bias folded. LDS: 64KB Wxp slab, aliased by pl after loop.
template<bool XBF16>
__global__ __launch_bounds__(256, 2) void gx_prepass(
    const void* __restrict__ xsrc, const unsigned short* __restrict__ Wxp,
    const float* __restrict__ bp, _Float16* __restrict__ Gx)
{
    __shared__ char smem[65536];
    const int bid = blockIdx.x;
    const int c = bid & 7;
    const int i = bid >> 3;
    const int mt = c * 16 + (i >> 7);
    const int js = i & 127;
    const int tid = threadIdx.x;

    {   // stage Wxp slab (bf16 copy, XOR-swizzled)
        const int row = tid >> 3;
        const int sw = (row & 7) << 4;
        const unsigned short* src = Wxp + (size_t)(js * 32 + row) * 1024 + (tid & 7) * 128;
        char* dst = smem + row * 2048;
        #pragma unroll
        for (int it = 0; it < 16; ++it) {
            short8 v = *(const short8*)(src + it * 8);
            *(short8*)(dst + ((((tid & 7) * 256) + it * 16) ^ sw)) = v;
        }
    }
    __syncthreads();

    const int wave = tid >> 6, lane = tid & 63;
    const int arow = mt * 128 + wave * 32 + (lane & 31);
    const int k8 = (lane >> 5) * 8;
    const char* wrow = smem + (lane & 31) * 2048;
    const int sw2 = ((lane & 31) & 7) << 4;
    f32x16 a0 = {}, a1 = {};

    if (XBF16) {
        const unsigned short* xp = (const unsigned short*)xsrc + (size_t)arow * 1024 + k8;
        #pragma unroll 8
        for (int ks = 0; ks < 64; ++ks) {
            short8 a = *(const short8*)(xp + ks * 16);
            short8 b = *(const short8*)(wrow + ((ks * 32 + k8 * 2) ^ sw2));
            if (ks & 1) a1 = __builtin_amdgcn_mfma_f32_32x32x16_bf16(a, b, a1, 0, 0, 0);
            else        a0 = __builtin_amdgcn_mfma_f32_32x32x16_bf16(a, b, a0, 0, 0, 0);
        }
    } else {
        const float* Af = (const float*)xsrc + (size_t)arow * 1024 + k8;
        #pragma unroll 8
        for (int ks = 0; ks < 64; ++ks) {
            float4 lo = *(const float4*)(Af + ks * 16);
            float4 hi = *(const float4*)(Af + ks * 16 + 4);
            union { unsigned u32[4]; short8 v; } pk;
            pk.u32[0] = __builtin_amdgcn_perm(__float_as_uint(lo.y), __float_as_uint(lo.x), 0x07060302u);
            pk.u32[1] = __builtin_amdgcn_perm(__float_as_uint(lo.w), __float_as_uint(lo.z), 0x07060302u);
            pk.u32[2] = __builtin_amdgcn_perm(__float_as_uint(hi.y), __float_as_uint(hi.x), 0x07060302u);
            pk.u32[3] = __builtin_amdgcn_perm(__float_as_uint(hi.w), __float_as_uint(hi.z), 0x07060302u);
            short8 b = *(const short8*)(wrow + ((ks * 32 + k8 * 2) ^ sw2));
            if (ks & 1) a1 = __builtin_amdgcn_mfma_f32_32x32x16_bf16(pk.v, b, a1, 0, 0, 0);
            else        a0 = __builtin_amdgcn_mfma_f32_32x32x16_bf16(pk.v, b, a0, 0, 0, 0);
        }
    }
    f32x16 r = a0 + a1;
    __syncthreads();                               // all waves done reading W slab

    float* pl = (float*)smem;                      // alias: [128 rows][33]
    #pragma unroll
    for (int ii = 0; ii < 16; ++ii) {
        const int rowc = (ii & 3) + 8 * (ii >> 2) + 4 * (lane >> 5);
        pl[(wave * 32 + rowc) * 33 + (lane & 31)] = r[ii];
    }
    __syncthreads();

    {   // repack 4 packs/thread: (row, jj) -> 4 f16 gates, bias folded
        const int p0 = tid * 4;
        const int row = p0 >> 3;                   // 0..127
        const int jjb = p0 & 7;                    // 0 or 4
        __attribute__((aligned(16))) _Float16 vals[16];
        #pragma unroll
        for (int q = 0; q < 4; ++q) {
            const int jj = jjb + q;
            #pragma unroll
            for (int g = 0; g < 4; ++g) {
                float v = pl[row * 33 + g * 8 + jj] + bp[js * 32 + g * 8 + jj];
                vals[q * 4 + g] = (_Float16)v;
            }
        }
        _Float16* dst = Gx + ((size_t)(mt * 128 + row) * 4096 + js * 32 + jjb * 4);
        *(uint4*)dst       = *(uint4*)&vals[0];
        *(uint4*)(dst + 8) = *(uint4*)&vals[8];
    }
}

// ---------------- Tier A: persistent h-recurrence kernel ----------------
// 256 WGs (1/CU): bid = js*2 + bhh. WG: 64 batch rows x 8 j-cols (32 perm rows).
// 4 waves: mh=wave>>1 (32-row M-subtile), kh=wave&1 (K=512 half of h).
// Wh slab (64KB bf16, swizzled) staged once. Per step: poll flags -> h-GEMM ->
// pl reduce -> epilogue with prefetched Gx/mem -> h store (agent) -> flag.
__global__ __launch_bounds__(256, 1) void eplstm_h(
    const _Float16* __restrict__ Gx,  const float* __restrict__ mem,
    const float* __restrict__ Wh,     const float* __restrict__ c0,
    unsigned short* __restrict__ hseq, float* __restrict__ out,
    unsigned* __restrict__ gflag)
{
    extern __shared__ char smem[];                 // [0,64K): Wh slab; then pl
    float* pl = (float*)(smem + 65536);            // [4][32][PLW]

    const int bid = blockIdx.x;
    const int js = bid >> 1, bhh = bid & 1;
    const int tid = threadIdx.x;

    {   // stage Wh slab f32->bf16 swizzled
        const int row = tid >> 3;
        const int g = row >> 3, jj = row & 7;
        const int srow = (g + 1) * 1024 + js * 8 + jj;
        const int sw = (row & 7) << 4;
        const float* W = Wh + (size_t)srow * 1024;
        char* dst = smem + row * 2048;
        #pragma unroll
        for (int it = 0; it < 16; ++it) {
            const int k = (tid & 7) * 128 + it * 8;
            float4 lo = *(const float4*)(W + k);
            float4 hi = *(const float4*)(W + k + 4);
            union { unsigned short u[8]; short8 v; } pk;
            pk.u[0]=f2bf(lo.x); pk.u[1]=f2bf(lo.y); pk.u[2]=f2bf(lo.z); pk.u[3]=f2bf(lo.w);
            pk.u[4]=f2bf(hi.x); pk.u[5]=f2bf(hi.y); pk.u[6]=f2bf(hi.z); pk.u[7]=f2bf(hi.w);
            *(short8*)(dst + ((k * 2) ^ sw)) = pk.v;
        }
    }

    // epilogue constants (2 outputs/thread)
    const int e0 = tid * 2;
    const int row_e = e0 >> 3;                     // 0..63
    const int jj0 = e0 & 7;                        // even
    const int brow = bhh * 64 + row_e;
    const size_t obase = (size_t)brow * DH + js * 8 + jj0;
    const int mh_e = row_e >> 5, r_e = row_e & 31;
    float2 creg = *(const float2*)(c0 + obase);

    // wave constants
    const int wave = tid >> 6, lane = tid & 63;
    const int mh = wave >> 1, kh = wave & 1;
    const int arow = bhh * 64 + mh * 32 + (lane & 31);
    const int k8 = (lane >> 5) * 8;
    const char* wrow = smem + (lane & 31) * 2048;
    const int sw2 = ((lane & 31) & 7) << 4;
    const int kbyte0 = (kh * 512 + k8) * 2;
    const int p = lane & 31;
    const int word = (p & 7) * 4 + (p >> 3);       // jj*4 + g
    float* plw = pl + wave * 32 * PLW;
    unsigned long long* fb = (unsigned long long*)(gflag + bhh * 128);

    __syncthreads();

    for (int t = 0; t < T_STEPS; ++t) {
        // prefetch h-independent operands BEFORE the barrier wait
        uint4 gxv = *(const uint4*)(Gx + ((size_t)(t * BATCH + brow) * 4096 + js * 32 + jj0 * 4));
        float2 mv = *(const float2*)(mem + (size_t)t * BDH + obase);

        if (t > 0) {
            for (;;) {
                unsigned long long fv = __hip_atomic_load(&fb[lane], __ATOMIC_RELAXED,
                                                          __HIP_MEMORY_SCOPE_AGENT);
                if (__all(((unsigned)fv >= (unsigned)t) &&
                          ((unsigned)(fv >> 32) >= (unsigned)t))) break;
                __builtin_amdgcn_s_sleep(2);
            }
        }

        const unsigned short* hp = hseq + (size_t)t * BDH + (size_t)arow * DH + kh * 512 + k8;
        f32x16 a0 = {}, a1 = {};
        #pragma unroll 16
        for (int ks = 0; ks < 32; ++ks) {
            short8 a = *(const short8*)(hp + ks * 16);
            short8 b = *(const short8*)(wrow + ((kbyte0 + ks * 32) ^ sw2));
            if (ks & 1) a1 = __builtin_amdgcn_mfma_f32_32x32x16_bf16(a, b, a1, 0, 0, 0);
            else        a0 = __builtin_amdgcn_mfma_f32_32x32x16_bf16(a, b, a0, 0, 0, 0);
        }
        f32x16 r = a0 + a1;
        #pragma unroll
        for (int ii = 0; ii < 16; ++ii) {
            const int rowc = (ii & 3) + 8 * (ii >> 2) + 4 * (lane >> 5);
            plw[rowc * PLW + word] = r[ii];
        }
        __syncthreads();    // (A) partials visible

        float4 p0A = *(const float4*)(pl + (((mh_e << 1) | 0) * 32 + r_e) * PLW + (jj0 + 0) * 4);
        float4 p0B = *(const float4*)(pl + (((mh_e << 1) | 1) * 32 + r_e) * PLW + (jj0 + 0) * 4);
        float4 p1A = *(const float4*)(pl + (((mh_e << 1) | 0) * 32 + r_e) * PLW + (jj0 + 1) * 4);
        float4 p1B = *(const float4*)(pl + (((mh_e << 1) | 1) * 32 + r_e) * PLW + (jj0 + 1) * 4);
        union { uint4 u; _Float16 h[8]; } G; G.u = gxv;

        float hv[2];
        {
            const float gF = (float)G.h[0] + p0A.x + p0B.x;
            const float gG = (float)G.h[1] + p0A.y + p0B.y;
            const float gO = (float)G.h[2] + p0A.z + p0B.z;
            const float gR = (float)G.h[3] + p0A.w + p0B.w;
            const float ft = sigf(gF), ot = sigf(gO), rt = sigf(gR);
            const float gt = tanhfast(gG);
            const float cv = ft * creg.x + (1.f - ft) * gt + rt * tanhfast(mv.x);
            creg.x = cv;
            hv[0] = ot * tanhfast(cv);
        }
        {
            const float gF = (float)G.h[4] + p1A.x + p1B.x;
            const float gG = (float)G.h[5] + p1A.y + p1B.y;
            const float gO = (float)G.h[6] + p1A.z + p1B.z;
            const float gR = (float)G.h[7] + p1A.w + p1B.w;
            const float ft = sigf(gF), ot = sigf(gO), rt = sigf(gR);
            const float gt = tanhfast(gG);
            const float cv = ft * creg.y + (1.f - ft) * gt + rt * tanhfast(mv.y);
            creg.y = cv;
            hv[1] = ot * tanhfast(cv);
        }
        *(float2*)(out + (size_t)t * BDH + obase) = make_float2(hv[0], hv[1]);
        const unsigned hp2 = (unsigned)f2bf(hv[0]) | ((unsigned)f2bf(hv[1]) << 16);
        __hip_atomic_store((unsigned*)(hseq + (size_t)(t + 1) * BDH + obase), hp2,
                           __ATOMIC_RELAXED, __HIP_MEMORY_SCOPE_AGENT);

        __syncthreads();    // (B) pl consumed + every wave's stores drained (vmcnt0)
        if (tid == 0 && t < T_STEPS - 1) {
            __hip_atomic_store(&gflag[bhh * 128 + js], (unsigned)(t + 1),
                               __ATOMIC_RELEASE, __HIP_MEMORY_SCOPE_AGENT);
        }
    }
}

// ---------------- Tier C fallback: Round-3 persistent kernel (verbatim) ----------------
template<bool XBF16>
__global__ __launch_bounds__(256, 1) void eplstm_persistent(
    const void*  __restrict__ xsrc, const float* __restrict__ mem,
    const float* __restrict__ Wx,   const float* __restrict__ Wh,
    const float* __restrict__ bxp,  const float* __restrict__ bhp,
    const float* __restrict__ c0,
    unsigned short* __restrict__ hseq, float* __restrict__ out,
    unsigned* __restrict__ bar)
{
    extern __shared__ char smem[];
    float* pl = reinterpret_cast<float*>(smem + 131072);

    const int bid = blockIdx.x;
    const int js  = bid >> 1;
    const int bhh = bid & 1;
    const int tid = threadIdx.x;

    {
        const int prow = tid >> 3;
        const int g = prow >> 3, jj = prow & 7;
        const int srow = (g + 1) * 1024 + js * 8 + jj;
        const int kc = (tid & 7) * 256;
        const int sw = (prow & 7) << 4;
        for (int it = 0; it < 32; ++it) {
            const int k = kc + it * 8;
            const float* src = (k < DX) ? (Wx + (size_t)srow * DX + k)
                                        : (Wh + (size_t)srow * DH + (k - DX));
            float4 lo = reinterpret_cast<const float4*>(src)[0];
            float4 hi = reinterpret_cast<const float4*>(src)[1];
            union { unsigned short u[8]; short8 v; } pk;
            pk.u[0]=f2bf(lo.x); pk.u[1]=f2bf(lo.y); pk.u[2]=f2bf(lo.z); pk.u[3]=f2bf(lo.w);
            pk.u[4]=f2bf(hi.x); pk.u[5]=f2bf(hi.y); pk.u[6]=f2bf(hi.z); pk.u[7]=f2bf(hi.w);
            *reinterpret_cast<short8*>(smem + prow * 4096 + ((k * 2) ^ sw)) = pk.v;
        }
    }

    const int e0   = tid * 2;
    const int bl   = e0 >> 3;
    const int jj0  = e0 & 7;
    const int brow_g = bhh * 64 + bl;
    const size_t oidx = (size_t)brow_g * DH + js * 8 + jj0;
    float biasv[2][4];
    #pragma unroll
    for (int e2 = 0; e2 < 2; ++e2)
        #pragma unroll
        for (int g = 0; g < 4; ++g) {
            const int srow = (g + 1) * 1024 + js * 8 + jj0 + e2;
            biasv[e2][g] = bxp[srow] + bhp[srow];
        }
    float2 creg = *reinterpret_cast<const float2*>(c0 + oidx);
    const int mh_e = bl >> 5, rr = bl & 31;

    const int wave = tid >> 6;
    const int lane = tid & 63;
    const int mh = wave >> 1, kh = wave & 1;
    const int arow   = bhh * 64 + mh * 32 + (lane & 31);
    const int k8     = (lane >> 5) * 8;
    const int brow   = lane & 31;
    const char* bbase = smem + brow * 4096;
    const int swz    = (brow & 7) << 4;
    const int kbyte0 = kh * 2048 + k8 * 2;

    __syncthreads();

    for (int t = 0; t < T_STEPS; ++t) {
        f32x16 ac0 = {}, ac1 = {}, ac2 = {}, ac3 = {};
        if (XBF16 || kh == 1) {
            const unsigned short* Ab = kh
                ? (hseq + (size_t)t * BDH + (size_t)arow * DH + k8)
                : ((const unsigned short*)xsrc + (size_t)t * BDX + (size_t)arow * DX + k8);
            #pragma unroll 8
            for (int ks = 0; ks < 64; ++ks) {
                short8 a = *reinterpret_cast<const short8*>(Ab + ks * 16);
                short8 b = *reinterpret_cast<const short8*>(bbase + ((kbyte0 + ks * 32) ^ swz));
                if      ((ks & 3) == 0) ac0 = __builtin_amdgcn_mfma_f32_32x32x16_bf16(a, b, ac0, 0, 0, 0);
                else if ((ks & 3) == 1) ac1 = __builtin_amdgcn_mfma_f32_32x32x16_bf16(a, b, ac1, 0, 0, 0);
                else if ((ks & 3) == 2) ac2 = __builtin_amdgcn_mfma_f32_32x32x16_bf16(a, b, ac2, 0, 0, 0);
                else                    ac3 = __builtin_amdgcn_mfma_f32_32x32x16_bf16(a, b, ac3, 0, 0, 0);
            }
        } else {
            const float* Af = (const float*)xsrc + (size_t)t * BDX + (size_t)arow * DX + k8;
            #pragma unroll 4
            for (int ks = 0; ks < 64; ++ks) {
                float4 lo = reinterpret_cast<const float4*>(Af + ks * 16)[0];
                float4 hi = reinterpret_cast<const float4*>(Af + ks * 16)[1];
                union { unsigned short u[8]; short8 v; } pk;
                pk.u[0]=f2bf(lo.x); pk.u[1]=f2bf(lo.y); pk.u[2]=f2bf(lo.z); pk.u[3]=f2bf(lo.w);
                pk.u[4]=f2bf(hi.x); pk.u[5]=f2bf(hi.y); pk.u[6]=f2bf(hi.z); pk.u[7]=f2bf(hi.w);
                short8 a = pk.v;
                short8 b = *reinterpret_cast<const short8*>(bbase + ((kbyte0 + ks * 32) ^ swz));
                if      ((ks & 3) == 0) ac0 = __builtin_amdgcn_mfma_f32_32x32x16_bf16(a, b, ac0, 0, 0, 0);
                else if ((ks & 3) == 1) ac1 = __builtin_amdgcn_mfma_f32_32x32x16_bf16(a, b, ac1, 0, 0, 0);
                else if ((ks & 3) == 2) ac2 = __builtin_amdgcn_mfma_f32_32x32x16_bf16(a, b, ac2, 0, 0, 0);
                else                    ac3 = __builtin_amdgcn_mfma_f32_32x32x16_bf16(a, b, ac3, 0, 0, 0);
            }
        }
        f32x16 r = (ac0 + ac1) + (ac2 + ac3);

        #pragma unroll
        for (int i = 0; i < 16; ++i) {
            const int row = (i & 3) + 8 * (i >> 2) + 4 * (lane >> 5);
            pl[(wave * 32 + row) * 33 + brow] = r[i];
        }
        __syncthreads();

        const float2 mt2 = *reinterpret_cast<const float2*>(mem + (size_t)t * BDH + oidx);
        float hv[2];
        #pragma unroll
        for (int e2 = 0; e2 < 2; ++e2) {
            const int jj = jj0 + e2;
            float gs[4];
            #pragma unroll
            for (int g = 0; g < 4; ++g) {
                const int col = g * 8 + jj;
                gs[g] = pl[((mh_e * 2 + 0) * 32 + rr) * 33 + col]
                      + pl[((mh_e * 2 + 1) * 32 + rr) * 33 + col]
                      + biasv[e2][g];
            }
            const float ft = 1.f / (1.f + expf(-gs[0]));
            const float gt = tanhf(gs[1]);
            const float ot = 1.f / (1.f + expf(-gs[2]));
            const float rt = 1.f / (1.f + expf(-gs[3]));
            const float cin = e2 ? creg.y : creg.x;
            const float mv  = e2 ? mt2.y : mt2.x;
            const float cv = ft * cin + (1.f - ft) * gt + rt * tanhf(mv);
            if (e2) creg.y = cv; else creg.x = cv;
            hv[e2] = ot * tanhf(cv);
        }
        *reinterpret_cast<float2*>(out + (size_t)t * BDH + oidx) = make_float2(hv[0], hv[1]);
        const unsigned hp = (unsigned)f2bf(hv[0]) | ((unsigned)f2bf(hv[1]) << 16);
        __hip_atomic_store((unsigned*)(hseq + (size_t)(t + 1) * BDH + oidx), hp,
                           __ATOMIC_RELAXED, __HIP_MEMORY_SCOPE_AGENT);

        __syncthreads();
        if (t < T_STEPS - 1) {
            if (tid == 0) {
                const unsigned want = (unsigned)(t + 1);
                const unsigned arrived = __hip_atomic_fetch_add(
                    &bar[bhh * 32], 1u, __ATOMIC_RELAXED, __HIP_MEMORY_SCOPE_AGENT);
                if (arrived == want * 128u - 1u) {
                    __hip_atomic_store(&bar[64 + bhh * 32], want,
                                       __ATOMIC_RELAXED, __HIP_MEMORY_SCOPE_AGENT);
                } else {
                    while (__hip_atomic_load(&bar[64 + bhh * 32],
                                             __ATOMIC_RELAXED, __HIP_MEMORY_SCOPE_AGENT) < want)
                        __builtin_amdgcn_s_sleep(2);
                }
            }
            __syncthreads();
        }
    }
}

extern "C" void kernel_launch(void* const* d_in, const int* in_sizes, int n_in,
                              void* d_out, int out_size, void* d_ws, size_t ws_size,
                              hipStream_t stream) {
    const float* inputs   = (const float*)d_in[0];
    const float* memories = (const float*)d_in[1];
    const float* h0       = (const float*)d_in[2];
    const float* c0       = (const float*)d_in[3];
    const float* Wx       = (const float*)d_in[4];
    const float* bx       = (const float*)d_in[5];
    const float* Wh       = (const float*)d_in[6];
    const float* bh_      = (const float*)d_in[7];
    float* outp = (float*)d_out;

    char* ws = (char*)d_ws;
    size_t off = 0;
    auto alloc = [&](size_t bytes) {
        char* p = ws + off;
        off = (off + bytes + 255) & ~(size_t)255;
        return p;
    };
    unsigned*       gflag = (unsigned*)alloc(256 * sizeof(unsigned));
    unsigned short* hseq  = (unsigned short*)alloc((size_t)(T_STEPS + 1) * BDH * 2);

    const size_t wxp_b  = (size_t)4096 * 1024 * 2;
    const size_t bp_b   = 4096 * 4;
    const size_t gx_b   = (size_t)16384 * 4096 * 2;
    const size_t xb_b   = (size_t)T_STEPS * BDX * 2;
    const size_t need_base = off + wxp_b + 256 + bp_b + 256 + gx_b + 256;
    const size_t need_xb   = need_base + xb_b + 256;

    if (ws_size >= need_base) {
        // ---------------- Tier A ----------------
        unsigned short* Wxp = (unsigned short*)alloc(wxp_b);
        float*          bp  = (float*)alloc(bp_b);
        _Float16*       Gx  = (_Float16*)alloc(gx_b);
        const bool use_xb = (ws_size >= need_xb);
        unsigned short* Xb = use_xb ? (unsigned short*)alloc(xb_b) : nullptr;

        init_seed<<<512, 256, 0, stream>>>(h0, hseq, gflag);
        prep_wxp<<<4096, 128, 0, stream>>>(Wx, bx, bh_, Wxp, bp);
        if (use_xb) {
            prep_x<<<8192, 256, 0, stream>>>(inputs, Xb);
            gx_prepass<true><<<16384, 256, 0, stream>>>((const void*)Xb, Wxp, bp, Gx);
        } else {
            gx_prepass<false><<<16384, 256, 0, stream>>>((const void*)inputs, Wxp, bp, Gx);
        }

        const unsigned smem_bytes = 65536 + 4 * 32 * PLW * 4;   // 86016
        (void)hipFuncSetAttribute((const void*)eplstm_h,
                                  hipFuncAttributeMaxDynamicSharedMemorySize, smem_bytes);
        void* kargs[] = { (void*)&Gx, (void*)&memories, (void*)&Wh, (void*)&c0,
                          (void*)&hseq, (void*)&outp, (void*)&gflag };
        hipError_t err = hipLaunchCooperativeKernel((const void*)eplstm_h, dim3(256),
                                                    dim3(256), kargs, smem_bytes, stream);
        if (err != hipSuccess) {
            eplstm_h<<<256, 256, smem_bytes, stream>>>(Gx, memories, Wh, c0,
                                                       hseq, outp, gflag);
        }
    } else {
        // ---------------- Tier C: Round-3 path ----------------
        const bool use_xb = (ws_size >= off + xb_b + 256);
        unsigned short* Xb = use_xb ? (unsigned short*)alloc(xb_b) : nullptr;

        init_seed<<<512, 256, 0, stream>>>(h0, hseq, gflag);
        if (use_xb) prep_x<<<8192, 256, 0, stream>>>(inputs, Xb);

        const unsigned smem_bytes = 131072 + 9216 + 9216 + 64;
        const void* xsrc = use_xb ? (const void*)Xb : (const void*)inputs;
        if (use_xb) {
            (void)hipFuncSetAttribute((const void*)eplstm_persistent<true>,
                                      hipFuncAttributeMaxDynamicSharedMemorySize, smem_bytes);
            void* kargs[] = { (void*)&xsrc, (void*)&memories, (void*)&Wx, (void*)&Wh,
                              (void*)&bx, (void*)&bh_, (void*)&c0, (void*)&hseq,
                              (void*)&outp, (void*)&gflag };
            hipError_t err = hipLaunchCooperativeKernel(
                (const void*)eplstm_persistent<true>, dim3(256), dim3(256),
                kargs, smem_bytes, stream);
            if (err != hipSuccess) {
                eplstm_persistent<true><<<256, 256, smem_bytes, stream>>>(
                    xsrc, memories, Wx, Wh, bx, bh_, c0, hseq, outp, gflag);
            }
        } else {
            (void)hipFuncSetAttribute((const void*)eplstm_persistent<false>,
                                      hipFuncAttributeMaxDynamicSharedMemorySize, smem_bytes);
            void* kargs[] = { (void*)&xsrc, (void*)&memories, (void*)&Wx, (void*)&Wh,
                              (void*)&bx, (void*)&bh_, (void*)&c0, (void*)&hseq,
                              (void*)&outp, (void*)&gflag };
            hipError_t err = hipLaunchCooperativeKernel(
                (const void*)eplstm_persistent<false>, dim3(256), dim3(256),
                kargs, smem_bytes, stream);
            if (err != hipSuccess) {
                eplstm_persistent<false><<<256, 256, smem_bytes, stream>>>(
                    xsrc, memories, Wx, Wh, bx, bh_, c0, hseq, outp, gflag);
            }
        }
    }
}

// Round 6
// 1554.462 us; speedup vs baseline: 2.2839x; 2.0197x over previous
//
#include <hip/hip_runtime.h>

#define T_STEPS 128
#define BATCH   128
#define DX      1024
#define DH      1024
#define BDH     (BATCH * DH)   // 131072
#define BDX     (BATCH * DX)
#define PLW     40             // eplstm_h pl row stride (words)

typedef __attribute__((ext_vector_type(8)))  short short8;
typedef __attribute__((ext_vector_type(16))) float f32x16;

static __device__ __forceinline__ unsigned short f2bf(float f) {
    union { float f; unsigned u; } v; v.f = f;
    unsigned r = v.u + 0x7fffu + ((v.u >> 16) & 1u);   // RNE
    return (unsigned short)(r >> 16);
}
static __device__ __forceinline__ float sigf(float x) {
    float u = __expf(-fabsf(x));
    float b = 1.0f / (1.0f + u);
    return x >= 0.0f ? b : 1.0f - b;
}
static __device__ __forceinline__ float tanhfast(float x) {
    float u = __expf(-2.0f * fabsf(x));
    float r = (1.0f - u) / (1.0f + u);
    return x >= 0.0f ? r : -r;
}

// ---------------- prep kernels ----------------

__global__ __launch_bounds__(256) void prep_x(const float* __restrict__ x,
                                              unsigned short* __restrict__ Xb) {
    const size_t i8 = ((size_t)blockIdx.x * 256 + threadIdx.x) * 8;
    float4 lo = reinterpret_cast<const float4*>(x + i8)[0];
    float4 hi = reinterpret_cast<const float4*>(x + i8)[1];
    union { unsigned short u[8]; short8 v; } pk;
    pk.u[0]=f2bf(lo.x); pk.u[1]=f2bf(lo.y); pk.u[2]=f2bf(lo.z); pk.u[3]=f2bf(lo.w);
    pk.u[4]=f2bf(hi.x); pk.u[5]=f2bf(hi.y); pk.u[6]=f2bf(hi.z); pk.u[7]=f2bf(hi.w);
    *reinterpret_cast<short8*>(Xb + i8) = pk.v;
}

__global__ __launch_bounds__(256) void init_seed(const float* __restrict__ h0,
                                                 unsigned short* __restrict__ hseq,
                                                 unsigned* __restrict__ gflag) {
    const int i = blockIdx.x * 256 + threadIdx.x;
    if (i < BDH) hseq[i] = f2bf(h0[i]);
    if (blockIdx.x == 0) gflag[threadIdx.x] = 0;     // 256 flag words
}

// Wxp[p][k] bf16 (perm row p = js*32 + g*8 + jj, gates F,G,O,R; I elided),
// bp[p] = bx+bh folded bias.
__global__ __launch_bounds__(128) void prep_wxp(const float* __restrict__ Wx,
                                                const float* __restrict__ bx,
                                                const float* __restrict__ bh,
                                                unsigned short* __restrict__ Wxp,
                                                float* __restrict__ bp) {
    const int p = blockIdx.x;                        // 0..4095
    const int js = p >> 5, g = (p >> 3) & 3, jj = p & 7;
    const int srow = (g + 1) * 1024 + js * 8 + jj;
    const int k = threadIdx.x * 8;                   // 0..1016
    float4 lo = *(const float4*)(Wx + (size_t)srow * DX + k);
    float4 hi = *(const float4*)(Wx + (size_t)srow * DX + k + 4);
    union { unsigned short u[8]; short8 v; } pk;
    pk.u[0]=f2bf(lo.x); pk.u[1]=f2bf(lo.y); pk.u[2]=f2bf(lo.z); pk.u[3]=f2bf(lo.w);
    pk.u[4]=f2bf(hi.x); pk.u[5]=f2bf(hi.y); pk.u[6]=f2bf(hi.z); pk.u[7]=f2bf(hi.w);
    *reinterpret_cast<short8*>(Wxp + (size_t)p * 1024 + k) = pk.v;
    if (threadIdx.x == 0) bp[p] = bx[srow] + bh[srow];
}

// ---------------- Gx prepass v2: persistent over 16 timesteps ----------------
// Grid 512: c = bid&7 (XCD chunk -> timesteps c*16..+16), jp = bid>>3 (0..63,
// js-pair -> 64 perm rows). Stage 128KB W slab ONCE, loop 16 mts:
// M=128 (full batch) x N=64, K=1024; A read once per mt (shared by both
// N-tiles). pl is f16 [128][72]; repack adds bias, stores Gx f16.
template<bool XBF16>
__global__ __launch_bounds__(256, 1) void gx_prepass2(
    const void* __restrict__ xsrc, const unsigned short* __restrict__ Wxp,
    const float* __restrict__ bp, _Float16* __restrict__ Gx)
{
    extern __shared__ char sm[];                  // [0,128K): W slab; then pl16
    _Float16* pl16 = (_Float16*)(sm + 131072);    // [128][72]

    const int bid = blockIdx.x;
    const int c  = bid & 7;
    const int jp = bid >> 3;                      // 0..63
    const int tid = threadIdx.x;

    {   // stage W slab: 64 perm rows [jp*64, +64), swizzled
        const int row = tid >> 2;                 // 0..63
        const int chunk = tid & 3;
        const int sw = (row & 7) << 4;
        const unsigned short* src = Wxp + (size_t)(jp * 64 + row) * 1024;
        char* dst = sm + row * 2048;
        #pragma unroll
        for (int j = 0; j < 32; ++j) {
            const int off = chunk * 16 + j * 64;
            short8 v = *(const short8*)(src + (off >> 1));
            *(short8*)(dst + (off ^ sw)) = v;
        }
    }

    // hoisted bias for repack: bias_f[jsl][q*4+g] for this thread's (row,jjb)
    const int rrow = tid >> 1;
    const int jjb  = (tid & 1) * 4;
    float bias_f[2][16];
    #pragma unroll
    for (int jsl = 0; jsl < 2; ++jsl)
        #pragma unroll
        for (int q = 0; q < 4; ++q)
            #pragma unroll
            for (int g = 0; g < 4; ++g)
                bias_f[jsl][q * 4 + g] = bp[(jp * 2 + jsl) * 32 + g * 8 + (jjb + q)];

    const int wave = tid >> 6, lane = tid & 63;
    const int k8 = (lane >> 5) * 8;
    const char* wrow0 = sm + (lane & 31) * 2048;
    const char* wrow1 = wrow0 + 32 * 2048;
    const int sw2 = ((lane & 31) & 7) << 4;
    __syncthreads();

    for (int i = 0; i < 16; ++i) {
        const int mt = c * 16 + i;                // timestep
        const int arow = mt * 128 + wave * 32 + (lane & 31);
        f32x16 a00 = {}, a01 = {}, a10 = {}, a11 = {};

        if (XBF16) {
            const unsigned short* xp = (const unsigned short*)xsrc + (size_t)arow * 1024 + k8;
            #pragma unroll 8
            for (int ks = 0; ks < 64; ++ks) {
                short8 a  = *(const short8*)(xp + ks * 16);
                short8 b0 = *(const short8*)(wrow0 + ((ks * 32 + k8 * 2) ^ sw2));
                short8 b1 = *(const short8*)(wrow1 + ((ks * 32 + k8 * 2) ^ sw2));
                if (ks & 1) {
                    a01 = __builtin_amdgcn_mfma_f32_32x32x16_bf16(a, b0, a01, 0, 0, 0);
                    a11 = __builtin_amdgcn_mfma_f32_32x32x16_bf16(a, b1, a11, 0, 0, 0);
                } else {
                    a00 = __builtin_amdgcn_mfma_f32_32x32x16_bf16(a, b0, a00, 0, 0, 0);
                    a10 = __builtin_amdgcn_mfma_f32_32x32x16_bf16(a, b1, a10, 0, 0, 0);
                }
            }
        } else {
            const float* Af = (const float*)xsrc + (size_t)arow * 1024 + k8;
            #pragma unroll 8
            for (int ks = 0; ks < 64; ++ks) {
                float4 lo = *(const float4*)(Af + ks * 16);
                float4 hi = *(const float4*)(Af + ks * 16 + 4);
                union { unsigned u32[4]; short8 v; } pk;
                pk.u32[0] = __builtin_amdgcn_perm(__float_as_uint(lo.y), __float_as_uint(lo.x), 0x07060302u);
                pk.u32[1] = __builtin_amdgcn_perm(__float_as_uint(lo.w), __float_as_uint(lo.z), 0x07060302u);
                pk.u32[2] = __builtin_amdgcn_perm(__float_as_uint(hi.y), __float_as_uint(hi.x), 0x07060302u);
                pk.u32[3] = __builtin_amdgcn_perm(__float_as_uint(hi.w), __float_as_uint(hi.z), 0x07060302u);
                short8 b0 = *(const short8*)(wrow0 + ((ks * 32 + k8 * 2) ^ sw2));
                short8 b1 = *(const short8*)(wrow1 + ((ks * 32 + k8 * 2) ^ sw2));
                if (ks & 1) {
                    a01 = __builtin_amdgcn_mfma_f32_32x32x16_bf16(pk.v, b0, a01, 0, 0, 0);
                    a11 = __builtin_amdgcn_mfma_f32_32x32x16_bf16(pk.v, b1, a11, 0, 0, 0);
                } else {
                    a00 = __builtin_amdgcn_mfma_f32_32x32x16_bf16(pk.v, b0, a00, 0, 0, 0);
                    a10 = __builtin_amdgcn_mfma_f32_32x32x16_bf16(pk.v, b1, a10, 0, 0, 0);
                }
            }
        }
        f32x16 r0 = a00 + a01;
        f32x16 r1 = a10 + a11;

        #pragma unroll
        for (int ii = 0; ii < 16; ++ii) {
            const int rowc = (ii & 3) + 8 * (ii >> 2) + 4 * (lane >> 5);
            pl16[(wave * 32 + rowc) * 72 + (lane & 31)]      = (_Float16)r0[ii];
            pl16[(wave * 32 + rowc) * 72 + 32 + (lane & 31)] = (_Float16)r1[ii];
        }
        __syncthreads();   // pl written

        #pragma unroll
        for (int jsl = 0; jsl < 2; ++jsl) {
            __attribute__((aligned(16))) _Float16 vals[16];
            #pragma unroll
            for (int q = 0; q < 4; ++q)
                #pragma unroll
                for (int g = 0; g < 4; ++g)
                    vals[q * 4 + g] = (_Float16)(
                        (float)pl16[rrow * 72 + jsl * 32 + g * 8 + (jjb + q)]
                        + bias_f[jsl][q * 4 + g]);
            _Float16* dst = Gx + ((size_t)(mt * 128 + rrow) * 4096
                                  + (jp * 2 + jsl) * 32 + jjb * 4);
            *(uint4*)dst       = *(uint4*)&vals[0];
            *(uint4*)(dst + 8) = *(uint4*)&vals[8];
        }
        __syncthreads();   // pl consumed before next mt overwrites
    }
}

// ---------------- persistent h-recurrence kernel ----------------
// 256 WGs (1/CU): bid = js*2 + bhh. WG: 64 batch rows x 8 j-cols (32 perm rows).
// 4 waves: mh=wave>>1 (32-row M-subtile), kh=wave&1 (K=512 half of h).
// Per step: prefetch Gx/mem -> poll flags (agent atomics, bypass L2) ->
// h-GEMM -> pl reduce -> epilogue -> h store (agent) -> vmcnt drain ->
// RELAXED flag (NO release: release emits buffer_wbl2 = full L2 writeback,
// the R5 regression).
__global__ __launch_bounds__(256, 1) void eplstm_h(
    const _Float16* __restrict__ Gx,  const float* __restrict__ mem,
    const float* __restrict__ Wh,     const float* __restrict__ c0,
    unsigned short* __restrict__ hseq, float* __restrict__ out,
    unsigned* __restrict__ gflag)
{
    extern __shared__ char smem[];                 // [0,64K): Wh slab; then pl
    float* pl = (float*)(smem + 65536);            // [4][32][PLW]

    const int bid = blockIdx.x;
    const int js = bid >> 1, bhh = bid & 1;
    const int tid = threadIdx.x;

    {   // stage Wh slab f32->bf16 swizzled
        const int row = tid >> 3;
        const int g = row >> 3, jj = row & 7;
        const int srow = (g + 1) * 1024 + js * 8 + jj;
        const int sw = (row & 7) << 4;
        const float* W = Wh + (size_t)srow * 1024;
        char* dst = smem + row * 2048;
        #pragma unroll
        for (int it = 0; it < 16; ++it) {
            const int k = (tid & 7) * 128 + it * 8;
            float4 lo = *(const float4*)(W + k);
            float4 hi = *(const float4*)(W + k + 4);
            union { unsigned short u[8]; short8 v; } pk;
            pk.u[0]=f2bf(lo.x); pk.u[1]=f2bf(lo.y); pk.u[2]=f2bf(lo.z); pk.u[3]=f2bf(lo.w);
            pk.u[4]=f2bf(hi.x); pk.u[5]=f2bf(hi.y); pk.u[6]=f2bf(hi.z); pk.u[7]=f2bf(hi.w);
            *(short8*)(dst + ((k * 2) ^ sw)) = pk.v;
        }
    }

    // epilogue constants (2 outputs/thread)
    const int e0 = tid * 2;
    const int row_e = e0 >> 3;                     // 0..63
    const int jj0 = e0 & 7;                        // even
    const int brow = bhh * 64 + row_e;
    const size_t obase = (size_t)brow * DH + js * 8 + jj0;
    const int mh_e = row_e >> 5, r_e = row_e & 31;
    float2 creg = *(const float2*)(c0 + obase);

    // wave constants
    const int wave = tid >> 6, lane = tid & 63;
    const int mh = wave >> 1, kh = wave & 1;
    const int arow = bhh * 64 + mh * 32 + (lane & 31);
    const int k8 = (lane >> 5) * 8;
    const char* wrow = smem + (lane & 31) * 2048;
    const int sw2 = ((lane & 31) & 7) << 4;
    const int kbyte0 = (kh * 512 + k8) * 2;
    const int p = lane & 31;
    const int word = (p & 7) * 4 + (p >> 3);       // jj*4 + g
    float* plw = pl + wave * 32 * PLW;
    unsigned long long* fb = (unsigned long long*)(gflag + bhh * 128);

    __syncthreads();

    for (int t = 0; t < T_STEPS; ++t) {
        // prefetch h-independent operands BEFORE the barrier wait
        uint4 gxv = *(const uint4*)(Gx + ((size_t)(t * BATCH + brow) * 4096 + js * 32 + jj0 * 4));
        float2 mv = *(const float2*)(mem + (size_t)t * BDH + obase);

        if (t > 0) {
            for (;;) {
                unsigned long long fv = __hip_atomic_load(&fb[lane], __ATOMIC_RELAXED,
                                                          __HIP_MEMORY_SCOPE_AGENT);
                if (__all(((unsigned)fv >= (unsigned)t) &&
                          ((unsigned)(fv >> 32) >= (unsigned)t))) break;
                __builtin_amdgcn_s_sleep(1);
            }
        }

        const unsigned short* hp = hseq + (size_t)t * BDH + (size_t)arow * DH + kh * 512 + k8;
        f32x16 a0 = {}, a1 = {};
        #pragma unroll 16
        for (int ks = 0; ks < 32; ++ks) {
            short8 a = *(const short8*)(hp + ks * 16);
            short8 b = *(const short8*)(wrow + ((kbyte0 + ks * 32) ^ sw2));
            if (ks & 1) a1 = __builtin_amdgcn_mfma_f32_32x32x16_bf16(a, b, a1, 0, 0, 0);
            else        a0 = __builtin_amdgcn_mfma_f32_32x32x16_bf16(a, b, a0, 0, 0, 0);
        }
        f32x16 r = a0 + a1;
        #pragma unroll
        for (int ii = 0; ii < 16; ++ii) {
            const int rowc = (ii & 3) + 8 * (ii >> 2) + 4 * (lane >> 5);
            plw[rowc * PLW + word] = r[ii];
        }
        __syncthreads();    // (A) partials visible

        float4 p0A = *(const float4*)(pl + (((mh_e << 1) | 0) * 32 + r_e) * PLW + (jj0 + 0) * 4);
        float4 p0B = *(const float4*)(pl + (((mh_e << 1) | 1) * 32 + r_e) * PLW + (jj0 + 0) * 4);
        float4 p1A = *(const float4*)(pl + (((mh_e << 1) | 0) * 32 + r_e) * PLW + (jj0 + 1) * 4);
        float4 p1B = *(const float4*)(pl + (((mh_e << 1) | 1) * 32 + r_e) * PLW + (jj0 + 1) * 4);
        union { uint4 u; _Float16 h[8]; } G; G.u = gxv;

        float hv[2];
        {
            const float gF = (float)G.h[0] + p0A.x + p0B.x;
            const float gG = (float)G.h[1] + p0A.y + p0B.y;
            const float gO = (float)G.h[2] + p0A.z + p0B.z;
            const float gR = (float)G.h[3] + p0A.w + p0B.w;
            const float ft = sigf(gF), ot = sigf(gO), rt = sigf(gR);
            const float gt = tanhfast(gG);
            const float cv = ft * creg.x + (1.f - ft) * gt + rt * tanhfast(mv.x);
            creg.x = cv;
            hv[0] = ot * tanhfast(cv);
        }
        {
            const float gF = (float)G.h[4] + p1A.x + p1B.x;
            const float gG = (float)G.h[5] + p1A.y + p1B.y;
            const float gO = (float)G.h[6] + p1A.z + p1B.z;
            const float gR = (float)G.h[7] + p1A.w + p1B.w;
            const float ft = sigf(gF), ot = sigf(gO), rt = sigf(gR);
            const float gt = tanhfast(gG);
            const float cv = ft * creg.y + (1.f - ft) * gt + rt * tanhfast(mv.y);
            creg.y = cv;
            hv[1] = ot * tanhfast(cv);
        }
        *(float2*)(out + (size_t)t * BDH + obase) = make_float2(hv[0], hv[1]);
        const unsigned hp2 = (unsigned)f2bf(hv[0]) | ((unsigned)f2bf(hv[1]) << 16);
        __hip_atomic_store((unsigned*)(hseq + (size_t)(t + 1) * BDH + obase), hp2,
                           __ATOMIC_RELAXED, __HIP_MEMORY_SCOPE_AGENT);

        asm volatile("s_waitcnt vmcnt(0)" ::: "memory");   // h stores ACKed at LLC
        __syncthreads();    // (B) all waves drained; pl reusable
        if (tid == 0 && t < T_STEPS - 1) {
            __hip_atomic_store(&gflag[bhh * 128 + js], (unsigned)(t + 1),
                               __ATOMIC_RELAXED, __HIP_MEMORY_SCOPE_AGENT);
        }
    }
}

// ---------------- Tier C fallback: Round-3 persistent kernel (verbatim) ----------------
template<bool XBF16>
__global__ __launch_bounds__(256, 1) void eplstm_persistent(
    const void*  __restrict__ xsrc, const float* __restrict__ mem,
    const float* __restrict__ Wx,   const float* __restrict__ Wh,
    const float* __restrict__ bxp,  const float* __restrict__ bhp,
    const float* __restrict__ c0,
    unsigned short* __restrict__ hseq, float* __restrict__ out,
    unsigned* __restrict__ bar)
{
    extern __shared__ char smem[];
    float* pl = reinterpret_cast<float*>(smem + 131072);

    const int bid = blockIdx.x;
    const int js  = bid >> 1;
    const int bhh = bid & 1;
    const int tid = threadIdx.x;

    {
        const int prow = tid >> 3;
        const int g = prow >> 3, jj = prow & 7;
        const int srow = (g + 1) * 1024 + js * 8 + jj;
        const int kc = (tid & 7) * 256;
        const int sw = (prow & 7) << 4;
        for (int it = 0; it < 32; ++it) {
            const int k = kc + it * 8;
            const float* src = (k < DX) ? (Wx + (size_t)srow * DX + k)
                                        : (Wh + (size_t)srow * DH + (k - DX));
            float4 lo = reinterpret_cast<const float4*>(src)[0];
            float4 hi = reinterpret_cast<const float4*>(src)[1];
            union { unsigned short u[8]; short8 v; } pk;
            pk.u[0]=f2bf(lo.x); pk.u[1]=f2bf(lo.y); pk.u[2]=f2bf(lo.z); pk.u[3]=f2bf(lo.w);
            pk.u[4]=f2bf(hi.x); pk.u[5]=f2bf(hi.y); pk.u[6]=f2bf(hi.z); pk.u[7]=f2bf(hi.w);
            *reinterpret_cast<short8*>(smem + prow * 4096 + ((k * 2) ^ sw)) = pk.v;
        }
    }

    const int e0   = tid * 2;
    const int bl   = e0 >> 3;
    const int jj0  = e0 & 7;
    const int brow_g = bhh * 64 + bl;
    const size_t oidx = (size_t)brow_g * DH + js * 8 + jj0;
    float biasv[2][4];
    #pragma unroll
    for (int e2 = 0; e2 < 2; ++e2)
        #pragma unroll
        for (int g = 0; g < 4; ++g) {
            const int srow = (g + 1) * 1024 + js * 8 + jj0 + e2;
            biasv[e2][g] = bxp[srow] + bhp[srow];
        }
    float2 creg = *reinterpret_cast<const float2*>(c0 + oidx);
    const int mh_e = bl >> 5, rr = bl & 31;

    const int wave = tid >> 6;
    const int lane = tid & 63;
    const int mh = wave >> 1, kh = wave & 1;
    const int arow   = bhh * 64 + mh * 32 + (lane & 31);
    const int k8     = (lane >> 5) * 8;
    const int brow   = lane & 31;
    const char* bbase = smem + brow * 4096;
    const int swz    = (brow & 7) << 4;
    const int kbyte0 = kh * 2048 + k8 * 2;

    __syncthreads();

    for (int t = 0; t < T_STEPS; ++t) {
        f32x16 ac0 = {}, ac1 = {}, ac2 = {}, ac3 = {};
        if (XBF16 || kh == 1) {
            const unsigned short* Ab = kh
                ? (hseq + (size_t)t * BDH + (size_t)arow * DH + k8)
                : ((const unsigned short*)xsrc + (size_t)t * BDX + (size_t)arow * DX + k8);
            #pragma unroll 8
            for (int ks = 0; ks < 64; ++ks) {
                short8 a = *reinterpret_cast<const short8*>(Ab + ks * 16);
                short8 b = *reinterpret_cast<const short8*>(bbase + ((kbyte0 + ks * 32) ^ swz));
                if      ((ks & 3) == 0) ac0 = __builtin_amdgcn_mfma_f32_32x32x16_bf16(a, b, ac0, 0, 0, 0);
                else if ((ks & 3) == 1) ac1 = __builtin_amdgcn_mfma_f32_32x32x16_bf16(a, b, ac1, 0, 0, 0);
                else if ((ks & 3) == 2) ac2 = __builtin_amdgcn_mfma_f32_32x32x16_bf16(a, b, ac2, 0, 0, 0);
                else                    ac3 = __builtin_amdgcn_mfma_f32_32x32x16_bf16(a, b, ac3, 0, 0, 0);
            }
        } else {
            const float* Af = (const float*)xsrc + (size_t)t * BDX + (size_t)arow * DX + k8;
            #pragma unroll 4
            for (int ks = 0; ks < 64; ++ks) {
                float4 lo = reinterpret_cast<const float4*>(Af + ks * 16)[0];
                float4 hi = reinterpret_cast<const float4*>(Af + ks * 16)[1];
                union { unsigned short u[8]; short8 v; } pk;
                pk.u[0]=f2bf(lo.x); pk.u[1]=f2bf(lo.y); pk.u[2]=f2bf(lo.z); pk.u[3]=f2bf(lo.w);
                pk.u[4]=f2bf(hi.x); pk.u[5]=f2bf(hi.y); pk.u[6]=f2bf(hi.z); pk.u[7]=f2bf(hi.w);
                short8 a = pk.v;
                short8 b = *reinterpret_cast<const short8*>(bbase + ((kbyte0 + ks * 32) ^ swz));
                if      ((ks & 3) == 0) ac0 = __builtin_amdgcn_mfma_f32_32x32x16_bf16(a, b, ac0, 0, 0, 0);
                else if ((ks & 3) == 1) ac1 = __builtin_amdgcn_mfma_f32_32x32x16_bf16(a, b, ac1, 0, 0, 0);
                else if ((ks & 3) == 2) ac2 = __builtin_amdgcn_mfma_f32_32x32x16_bf16(a, b, ac2, 0, 0, 0);
                else                    ac3 = __builtin_amdgcn_mfma_f32_32x32x16_bf16(a, b, ac3, 0, 0, 0);
            }
        }
        f32x16 r = (ac0 + ac1) + (ac2 + ac3);

        #pragma unroll
        for (int i = 0; i < 16; ++i) {
            const int row = (i & 3) + 8 * (i >> 2) + 4 * (lane >> 5);
            pl[(wave * 32 + row) * 33 + brow] = r[i];
        }
        __syncthreads();

        const float2 mt2 = *reinterpret_cast<const float2*>(mem + (size_t)t * BDH + oidx);
        float hv[2];
        #pragma unroll
        for (int e2 = 0; e2 < 2; ++e2) {
            const int jj = jj0 + e2;
            float gs[4];
            #pragma unroll
            for (int g = 0; g < 4; ++g) {
                const int col = g * 8 + jj;
                gs[g] = pl[((mh_e * 2 + 0) * 32 + rr) * 33 + col]
                      + pl[((mh_e * 2 + 1) * 32 + rr) * 33 + col]
                      + biasv[e2][g];
            }
            const float ft = 1.f / (1.f + expf(-gs[0]));
            const float gt = tanhf(gs[1]);
            const float ot = 1.f / (1.f + expf(-gs[2]));
            const float rt = 1.f / (1.f + expf(-gs[3]));
            const float cin = e2 ? creg.y : creg.x;
            const float mv  = e2 ? mt2.y : mt2.x;
            const float cv = ft * cin + (1.f - ft) * gt + rt * tanhf(mv);
            if (e2) creg.y = cv; else creg.x = cv;
            hv[e2] = ot * tanhf(cv);
        }
        *reinterpret_cast<float2*>(out + (size_t)t * BDH + oidx) = make_float2(hv[0], hv[1]);
        const unsigned hp = (unsigned)f2bf(hv[0]) | ((unsigned)f2bf(hv[1]) << 16);
        __hip_atomic_store((unsigned*)(hseq + (size_t)(t + 1) * BDH + oidx), hp,
                           __ATOMIC_RELAXED, __HIP_MEMORY_SCOPE_AGENT);

        __syncthreads();
        if (t < T_STEPS - 1) {
            if (tid == 0) {
                const unsigned want = (unsigned)(t + 1);
                const unsigned arrived = __hip_atomic_fetch_add(
                    &bar[bhh * 32], 1u, __ATOMIC_RELAXED, __HIP_MEMORY_SCOPE_AGENT);
                if (arrived == want * 128u - 1u) {
                    __hip_atomic_store(&bar[64 + bhh * 32], want,
                                       __ATOMIC_RELAXED, __HIP_MEMORY_SCOPE_AGENT);
                } else {
                    while (__hip_atomic_load(&bar[64 + bhh * 32],
                                             __ATOMIC_RELAXED, __HIP_MEMORY_SCOPE_AGENT) < want)
                        __builtin_amdgcn_s_sleep(2);
                }
            }
            __syncthreads();
        }
    }
}

extern "C" void kernel_launch(void* const* d_in, const int* in_sizes, int n_in,
                              void* d_out, int out_size, void* d_ws, size_t ws_size,
                              hipStream_t stream) {
    const float* inputs   = (const float*)d_in[0];
    const float* memories = (const float*)d_in[1];
    const float* h0       = (const float*)d_in[2];
    const float* c0       = (const float*)d_in[3];
    const float* Wx       = (const float*)d_in[4];
    const float* bx       = (const float*)d_in[5];
    const float* Wh       = (const float*)d_in[6];
    const float* bh_      = (const float*)d_in[7];
    float* outp = (float*)d_out;

    char* ws = (char*)d_ws;
    size_t off = 0;
    auto alloc = [&](size_t bytes) {
        char* p = ws + off;
        off = (off + bytes + 255) & ~(size_t)255;
        return p;
    };
    unsigned*       gflag = (unsigned*)alloc(256 * sizeof(unsigned));
    unsigned short* hseq  = (unsigned short*)alloc((size_t)(T_STEPS + 1) * BDH * 2);

    const size_t wxp_b  = (size_t)4096 * 1024 * 2;
    const size_t bp_b   = 4096 * 4;
    const size_t gx_b   = (size_t)16384 * 4096 * 2;
    const size_t xb_b   = (size_t)T_STEPS * BDX * 2;
    const size_t need_base = off + wxp_b + 256 + bp_b + 256 + gx_b + 256;
    const size_t need_xb   = need_base + xb_b + 256;

    if (ws_size >= need_base) {
        // ---------------- Tier A ----------------
        unsigned short* Wxp = (unsigned short*)alloc(wxp_b);
        float*          bp  = (float*)alloc(bp_b);
        _Float16*       Gx  = (_Float16*)alloc(gx_b);
        const bool use_xb = (ws_size >= need_xb);
        unsigned short* Xb = use_xb ? (unsigned short*)alloc(xb_b) : nullptr;

        init_seed<<<512, 256, 0, stream>>>(h0, hseq, gflag);
        prep_wxp<<<4096, 128, 0, stream>>>(Wx, bx, bh_, Wxp, bp);

        const unsigned pre_smem = 131072 + 128 * 72 * 2;     // 149504
        if (use_xb) {
            prep_x<<<8192, 256, 0, stream>>>(inputs, Xb);
            (void)hipFuncSetAttribute((const void*)gx_prepass2<true>,
                                      hipFuncAttributeMaxDynamicSharedMemorySize, pre_smem);
            gx_prepass2<true><<<512, 256, pre_smem, stream>>>((const void*)Xb, Wxp, bp, Gx);
        } else {
            (void)hipFuncSetAttribute((const void*)gx_prepass2<false>,
                                      hipFuncAttributeMaxDynamicSharedMemorySize, pre_smem);
            gx_prepass2<false><<<512, 256, pre_smem, stream>>>((const void*)inputs, Wxp, bp, Gx);
        }

        const unsigned smem_bytes = 65536 + 4 * 32 * PLW * 4;   // 86016
        (void)hipFuncSetAttribute((const void*)eplstm_h,
                                  hipFuncAttributeMaxDynamicSharedMemorySize, smem_bytes);
        void* kargs[] = { (void*)&Gx, (void*)&memories, (void*)&Wh, (void*)&c0,
                          (void*)&hseq, (void*)&outp, (void*)&gflag };
        hipError_t err = hipLaunchCooperativeKernel((const void*)eplstm_h, dim3(256),
                                                    dim3(256), kargs, smem_bytes, stream);
        if (err != hipSuccess) {
            eplstm_h<<<256, 256, smem_bytes, stream>>>(Gx, memories, Wh, c0,
                                                       hseq, outp, gflag);
        }
    } else {
        // ---------------- Tier C: Round-3 path ----------------
        const bool use_xb = (ws_size >= off + xb_b + 256);
        unsigned short* Xb = use_xb ? (unsigned short*)alloc(xb_b) : nullptr;

        init_seed<<<512, 256, 0, stream>>>(h0, hseq, gflag);
        if (use_xb) prep_x<<<8192, 256, 0, stream>>>(inputs, Xb);

        const unsigned smem_bytes = 131072 + 9216 + 9216 + 64;
        const void* xsrc = use_xb ? (const void*)Xb : (const void*)inputs;
        if (use_xb) {
            (void)hipFuncSetAttribute((const void*)eplstm_persistent<true>,
                                      hipFuncAttributeMaxDynamicSharedMemorySize, smem_bytes);
            void* kargs[] = { (void*)&xsrc, (void*)&memories, (void*)&Wx, (void*)&Wh,
                              (void*)&bx, (void*)&bh_, (void*)&c0, (void*)&hseq,
                              (void*)&outp, (void*)&gflag };
            hipError_t err = hipLaunchCooperativeKernel(
                (const void*)eplstm_persistent<true>, dim3(256), dim3(256),
                kargs, smem_bytes, stream);
            if (err != hipSuccess) {
                eplstm_persistent<true><<<256, 256, smem_bytes, stream>>>(
                    xsrc, memories, Wx, Wh, bx, bh_, c0, hseq, outp, gflag);
            }
        } else {
            (void)hipFuncSetAttribute((const void*)eplstm_persistent<false>,
                                      hipFuncAttributeMaxDynamicSharedMemorySize, smem_bytes);
            void* kargs[] = { (void*)&xsrc, (void*)&memories, (void*)&Wx, (void*)&Wh,
                              (void*)&bx, (void*)&bh_, (void*)&c0, (void*)&hseq,
                              (void*)&outp, (void*)&gflag };
            hipError_t err = hipLaunchCooperativeKernel(
                (const void*)eplstm_persistent<false>, dim3(256), dim3(256),
                kargs, smem_bytes, stream);
            if (err != hipSuccess) {
                eplstm_persistent<false><<<256, 256, smem_bytes, stream>>>(
                    xsrc, memories, Wx, Wh, bx, bh_, c0, hseq, outp, gflag);
            }
        }
    }
}